// Round 7
// baseline (1201.736 us; speedup 1.0000x reference)
//
#include <hip/hip_runtime.h>
#include <hip/hip_bf16.h>
#include <math.h>

#define T_TOK 8192
#define H_DIM 1024
#define I_DIM 2816
#define N_EXP 8
#define NREG  16           // (expert, k) regions
#define CAP_SLOTS 18432    // 2*T + 16*128 alignment headroom
#define MAX_TILES 144      // CAP_SLOTS / 128

typedef __bf16 bf16x8 __attribute__((ext_vector_type(8)));
typedef __bf16 bf16x4 __attribute__((ext_vector_type(4)));
typedef float f32x4 __attribute__((ext_vector_type(4)));

__device__ inline void gload_lds16(const void* g, void* l) {
    __builtin_amdgcn_global_load_lds((const __attribute__((address_space(1))) void*)g,
                                     (__attribute__((address_space(3))) void*)l, 16, 0, 0);
}

// Bijective XCD-aware tile swizzle (m204): same-XCD blocks get contiguous ids.
__device__ inline void swz_tile(int& bx, int& by) {
    const int nx = gridDim.x;
    const int nwg = nx * gridDim.y;
    int lin = by * nx + bx;
    int q = nwg >> 3, r = nwg & 7, xcd = lin & 7, pos = lin >> 3;
    int swz = (xcd < r ? xcd * (q + 1) : r * (q + 1) + (xcd - r) * q) + pos;
    bx = swz % nx; by = swz / nx;
}

// f32 -> bf16, 4 elems/thread
__global__ void conv_kernel(const float* __restrict__ src, __bf16* __restrict__ dst, int n4) {
    int i = blockIdx.x * 256 + threadIdx.x;
    if (i < n4) {
        float4 v = ((const float4*)src)[i];
        bf16x4 o;
        o[0] = (__bf16)v.x; o[1] = (__bf16)v.y; o[2] = (__bf16)v.z; o[3] = (__bf16)v.w;
        ((bf16x4*)dst)[i] = o;
    }
}

// One wave per token: logits over 8 experts (float4-vectorized), softmax, top-2.
// No global atomics (R4->R5: atomic cacheline ping-pong cost ~190us).
__global__ void router_kernel(const float* __restrict__ x, const float* __restrict__ gw,
                              int* __restrict__ topi, float* __restrict__ topw) {
    int t = blockIdx.x * 4 + (threadIdx.x >> 6);
    int lane = threadIdx.x & 63;
    if (t >= T_TOK) return;
    const float4* xr = (const float4*)(x + (size_t)t * H_DIM);
    float s[N_EXP];
#pragma unroll
    for (int e = 0; e < N_EXP; e++) s[e] = 0.0f;
#pragma unroll
    for (int j = 0; j < H_DIM / 256; ++j) {
        float4 xv = xr[j * 64 + lane];
#pragma unroll
        for (int e = 0; e < N_EXP; e++) {
            float4 gv = ((const float4*)(gw + (size_t)e * H_DIM))[j * 64 + lane];
            s[e] += xv.x * gv.x + xv.y * gv.y + xv.z * gv.z + xv.w * gv.w;
        }
    }
#pragma unroll
    for (int off = 32; off; off >>= 1) {
#pragma unroll
        for (int e = 0; e < N_EXP; e++) s[e] += __shfl_xor(s[e], off);
    }
    if (lane == 0) {
        float m = s[0];
#pragma unroll
        for (int e = 1; e < N_EXP; e++) m = fmaxf(m, s[e]);
        float p[N_EXP]; float sum = 0.0f;
#pragma unroll
        for (int e = 0; e < N_EXP; e++) { p[e] = expf(s[e] - m); sum += p[e]; }
#pragma unroll
        for (int e = 0; e < N_EXP; e++) p[e] /= sum;
        int i0 = 0;
#pragma unroll
        for (int e = 1; e < N_EXP; e++) if (p[e] > p[i0]) i0 = e;
        int i1 = (i0 == 0) ? 1 : 0;
#pragma unroll
        for (int e = 0; e < N_EXP; e++) if (e != i0 && p[e] > p[i1]) i1 = e;
        float rs = p[i0] + p[i1] + 1e-20f;
        topi[t * 2 + 0] = i0; topi[t * 2 + 1] = i1;
        topw[t * 2 + 0] = p[i0] / rs; topw[t * 2 + 1] = p[i1] / rs;
    }
}

// Single-wave routing build: histogram -> bases -> tile tables -> slot assignment.
__global__ void route_build_kernel(const int* __restrict__ topi, const float* __restrict__ topw,
                                   int* __restrict__ token_ids, float* __restrict__ token_w,
                                   int* __restrict__ tile_e, int* __restrict__ tile_k) {
    __shared__ int h[64][NREG];
    __shared__ int bases[NREG];
    __shared__ int cur[64][NREG];
    const int lane = threadIdx.x;   // 0..63, single wave

    for (int i = lane; i < CAP_SLOTS; i += 64) token_ids[i] = -1;

#pragma unroll
    for (int r = 0; r < NREG; r++) h[lane][r] = 0;
    for (int i = 0; i < T_TOK * 2 / 64; i++) {
        int entry = i * 64 + lane;
        int r = topi[entry] * 2 + (entry & 1);
        h[lane][r]++;
    }
    __syncthreads();

    if (lane < NREG) {
        int c = 0;
        for (int l = 0; l < 64; l++) c += h[l][lane];
        bases[lane] = c;
    }
    __syncthreads();

    if (lane == 0) {
        int b = 0, t = 0;
        for (int r = 0; r < NREG; r++) {
            int c = bases[r];
            int nt = (c + 127) >> 7;
            bases[r] = b;
            for (int i = 0; i < nt; i++) { tile_e[t] = r >> 1; tile_k[t] = r & 1; t++; }
            b += nt << 7;
        }
        for (; t < MAX_TILES; t++) { tile_e[t] = -1; tile_k[t] = -1; }
    }
    __syncthreads();

    for (int r = 0; r < NREG; r++) {
        int s = bases[r];
        for (int l = 0; l < lane; l++) s += h[l][r];
        cur[lane][r] = s;
    }
    __syncthreads();

    for (int i = 0; i < T_TOK * 2 / 64; i++) {
        int entry = i * 64 + lane;
        int r = topi[entry] * 2 + (entry & 1);
        int slot = cur[lane][r]++;
        token_ids[slot] = entry >> 1;
        token_w[slot] = topw[entry];
    }
}

// Fused gate+up GEMM: 128x128 tile, BK=32, 4 waves, A staged once, both B's via
// gload_lds. hid = silu(A@Wg^T) * (A@Wu^T), written once (no RMW re-read).
template<int K>
__global__ __launch_bounds__(256, 3)
void gateup_fused(const __bf16* __restrict__ A,
                  const __bf16* __restrict__ Wg, const __bf16* __restrict__ Wu,
                  __bf16* __restrict__ hid,
                  const int* __restrict__ token_ids, const int* __restrict__ tile_e) {
    int bx = blockIdx.x, by = blockIdx.y;
    swz_tile(bx, by);
    int e = 0;
    if (tile_e) { e = tile_e[bx]; if (e < 0) return; }
    const int m0 = bx * 128, n0 = by * 128;

    __shared__ __bf16 As[2][128 * 32];
    __shared__ __bf16 Bg[2][128 * 32];
    __shared__ __bf16 Bu[2][128 * 32];

    const int tid = threadIdx.x, lane = tid & 63, wid = tid >> 6;
    const int wm = wid >> 1, wn = wid & 1;

    const int srow = wid * 16 + (lane >> 2);
    const int colb = (lane & 3) * 16;

    int ar0, ar1;
    if (tile_e) {
        int t0 = token_ids[m0 + srow], t1 = token_ids[m0 + srow + 64];
        ar0 = t0 < 0 ? 0 : t0;
        ar1 = t1 < 0 ? 0 : t1;
    } else {
        ar0 = m0 + srow; ar1 = m0 + srow + 64;
    }
    const char* pA0 = (const char*)A + (size_t)ar0 * (K * 2) + colb;
    const char* pA1 = (const char*)A + (size_t)ar1 * (K * 2) + colb;
    const char* pG0 = (const char*)Wg + ((size_t)e * I_DIM + n0 + srow) * (K * 2) + colb;
    const char* pG1 = pG0 + (size_t)64 * (K * 2);
    const char* pU0 = (const char*)Wu + ((size_t)e * I_DIM + n0 + srow) * (K * 2) + colb;
    const char* pU1 = pU0 + (size_t)64 * (K * 2);
    const int ldsoff = wid * 1024;

    f32x4 accg[4][4], accu[4][4];
    const f32x4 z4 = {0.f, 0.f, 0.f, 0.f};
#pragma unroll
    for (int i = 0; i < 4; i++)
#pragma unroll
        for (int j = 0; j < 4; j++) { accg[i][j] = z4; accu[i][j] = z4; }

    constexpr int NT = K / 32;

    auto stage = [&](int buf, int kt) {
        const size_t ko = (size_t)kt * 64;
        char* a_l = (char*)As[buf] + ldsoff;
        gload_lds16(pA0 + ko, a_l);
        gload_lds16(pA1 + ko, a_l + 4096);
        char* g_l = (char*)Bg[buf] + ldsoff;
        gload_lds16(pG0 + ko, g_l);
        gload_lds16(pG1 + ko, g_l + 4096);
        char* u_l = (char*)Bu[buf] + ldsoff;
        gload_lds16(pU0 + ko, u_l);
        gload_lds16(pU1 + ko, u_l + 4096);
    };

    auto compute = [&](int buf) {
        const int rA = wm * 64 + (lane & 15);
        const int rB = wn * 64 + (lane & 15);
        const int cK = (lane >> 4) * 8;
        bf16x8 a[4], g[4], u[4];
#pragma unroll
        for (int i = 0; i < 4; i++) a[i] = *(const bf16x8*)&As[buf][(rA + i * 16) * 32 + cK];
#pragma unroll
        for (int j = 0; j < 4; j++) {
            g[j] = *(const bf16x8*)&Bg[buf][(rB + j * 16) * 32 + cK];
            u[j] = *(const bf16x8*)&Bu[buf][(rB + j * 16) * 32 + cK];
        }
#pragma unroll
        for (int i = 0; i < 4; i++)
#pragma unroll
            for (int j = 0; j < 4; j++) {
                accg[i][j] = __builtin_amdgcn_mfma_f32_16x16x32_bf16(a[i], g[j], accg[i][j], 0, 0, 0);
                accu[i][j] = __builtin_amdgcn_mfma_f32_16x16x32_bf16(a[i], u[j], accu[i][j], 0, 0, 0);
            }
    };

    stage(0, 0);
    __syncthreads();
    int cur = 0;
    for (int kt = 0; kt < NT; ++kt) {
        if (kt + 1 < NT) stage(cur ^ 1, kt + 1);
        compute(cur);
        __syncthreads();
        cur ^= 1;
    }

    const int cb = lane & 15, rb = (lane >> 4) * 4;
#pragma unroll
    for (int i = 0; i < 4; i++)
#pragma unroll
        for (int j = 0; j < 4; j++)
#pragma unroll
            for (int r = 0; r < 4; r++) {
                const int row = wm * 64 + i * 16 + rb + r;
                const int col = n0 + wn * 64 + j * 16 + cb;
                float gv = accg[i][j][r];
                float uv = accu[i][j][r];
                float h = (gv / (1.0f + __expf(-gv))) * uv;
                hid[(size_t)(m0 + row) * I_DIM + col] = (__bf16)h;
            }
}

// m97-shape GEMM (R5-proven), now with XCD swizzle.
// EPI: 0=gate(silu->hid) 1=up(hid*=v) 2=down_shared(out=v) 3=down_routed(out[tok]+=w*v)
template<int EPI, int KDIM, int NBROWS>
__global__ __launch_bounds__(256, 4)
void gemm_k(const __bf16* __restrict__ A, const __bf16* __restrict__ B,
            __bf16* __restrict__ hid, float* __restrict__ out,
            const int* __restrict__ token_ids, const float* __restrict__ token_w,
            const int* __restrict__ tile_e, const int* __restrict__ tile_k, int ksel) {
    int bx = blockIdx.x, by = blockIdx.y;
    swz_tile(bx, by);
    int e = 0;
    if (tile_e) {
        e = tile_e[bx];
        if (e < 0) return;
        if (EPI == 3 && tile_k[bx] != ksel) return;
    }
    const int m0 = bx * 128, n0 = by * 128;

    __shared__ __bf16 As[2][128 * 32];
    __shared__ __bf16 Bs[2][128 * 32];

    const int tid = threadIdx.x, lane = tid & 63, wid = tid >> 6;
    const int wm = wid >> 1, wn = wid & 1;

    const int srow = wid * 16 + (lane >> 2);
    const int colb = (lane & 3) * 16;

    int ar0, ar1;
    if (EPI <= 1 && token_ids) {
        int t0 = token_ids[m0 + srow], t1 = token_ids[m0 + srow + 64];
        ar0 = t0 < 0 ? 0 : t0;
        ar1 = t1 < 0 ? 0 : t1;
    } else {
        ar0 = m0 + srow; ar1 = m0 + srow + 64;
    }
    const char* pA0 = (const char*)A + (size_t)ar0 * (KDIM * 2) + colb;
    const char* pA1 = (const char*)A + (size_t)ar1 * (KDIM * 2) + colb;
    const char* pB0 = (const char*)B + ((size_t)e * NBROWS + n0 + srow) * (KDIM * 2) + colb;
    const char* pB1 = pB0 + (size_t)64 * (KDIM * 2);
    const int ldsoff = wid * 1024;

    f32x4 acc[4][4];
    const f32x4 z4 = {0.f, 0.f, 0.f, 0.f};
#pragma unroll
    for (int i = 0; i < 4; i++)
#pragma unroll
        for (int j = 0; j < 4; j++) acc[i][j] = z4;

    constexpr int NT = KDIM / 32;

    auto stage = [&](int buf, int kt) {
        const size_t ko = (size_t)kt * 64;
        char* a_l = (char*)As[buf] + ldsoff;
        gload_lds16(pA0 + ko, a_l);
        gload_lds16(pA1 + ko, a_l + 4096);
        char* b_l = (char*)Bs[buf] + ldsoff;
        gload_lds16(pB0 + ko, b_l);
        gload_lds16(pB1 + ko, b_l + 4096);
    };

    auto compute = [&](int buf) {
        const int rA = wm * 64 + (lane & 15);
        const int rB = wn * 64 + (lane & 15);
        const int cK = (lane >> 4) * 8;
        bf16x8 a[4], b[4];
#pragma unroll
        for (int i = 0; i < 4; i++) a[i] = *(const bf16x8*)&As[buf][(rA + i * 16) * 32 + cK];
#pragma unroll
        for (int j = 0; j < 4; j++) b[j] = *(const bf16x8*)&Bs[buf][(rB + j * 16) * 32 + cK];
#pragma unroll
        for (int i = 0; i < 4; i++)
#pragma unroll
            for (int j = 0; j < 4; j++)
                acc[i][j] = __builtin_amdgcn_mfma_f32_16x16x32_bf16(a[i], b[j], acc[i][j], 0, 0, 0);
    };

    stage(0, 0);
    __syncthreads();
    int cur = 0;
    for (int kt = 0; kt < NT; ++kt) {
        if (kt + 1 < NT) stage(cur ^ 1, kt + 1);
        compute(cur);
        __syncthreads();
        cur ^= 1;
    }

    const int cb = lane & 15, rb = (lane >> 4) * 4;
#pragma unroll
    for (int i = 0; i < 4; i++)
#pragma unroll
        for (int j = 0; j < 4; j++)
#pragma unroll
            for (int r = 0; r < 4; r++) {
                const int row = wm * 64 + i * 16 + rb + r;
                const int col = n0 + wn * 64 + j * 16 + cb;
                float v = acc[i][j][r];
                if (EPI == 0) {
                    float sv = v / (1.0f + __expf(-v));
                    hid[(size_t)(m0 + row) * NBROWS + col] = (__bf16)sv;
                } else if (EPI == 1) {
                    size_t idx = (size_t)(m0 + row) * NBROWS + col;
                    hid[idx] = (__bf16)((float)hid[idx] * v);
                } else if (EPI == 2) {
                    out[(size_t)(m0 + row) * H_DIM + col] = v;
                } else {
                    int slot = m0 + row;
                    int tok = token_ids[slot];
                    if (tok >= 0) {
                        size_t o = (size_t)tok * H_DIM + col;
                        out[o] += token_w[slot] * v;   // k-split: no same-token race
                    }
                }
            }
}

extern "C" void kernel_launch(void* const* d_in, const int* in_sizes, int n_in,
                              void* d_out, int out_size, void* d_ws, size_t ws_size,
                              hipStream_t stream) {
    const float* x = (const float*)d_in[0];
    const float* gate_w = (const float*)d_in[1];
    const float* expert_gate = (const float*)d_in[2];
    const float* expert_up = (const float*)d_in[3];
    const float* expert_down = (const float*)d_in[4];
    const float* shared_gate = (const float*)d_in[5];
    const float* shared_up = (const float*)d_in[6];
    const float* shared_down = (const float*)d_in[7];
    float* out = (float*)d_out;

    char* w = (char*)d_ws;
    size_t off = 0;
    auto alloc = [&](size_t bytes) {
        void* p = w + off;
        off = (off + bytes + 255) & ~(size_t)255;
        return p;
    };

    const size_t wsz = (size_t)N_EXP * I_DIM * H_DIM * 2;   // 46.1 MB
    __bf16* xb = (__bf16*)alloc((size_t)T_TOK * H_DIM * 2);
    __bf16* wbufA = (__bf16*)alloc(wsz);
    __bf16* hid = (__bf16*)alloc((size_t)CAP_SLOTS * I_DIM * 2);
    int* topi = (int*)alloc((size_t)T_TOK * 2 * 4);
    float* topw = (float*)alloc((size_t)T_TOK * 2 * 4);
    int* tile_e = (int*)alloc(MAX_TILES * 4);
    int* tile_k = (int*)alloc(MAX_TILES * 4);
    int* token_ids = (int*)alloc((size_t)CAP_SLOTS * 4);
    float* token_w = (float*)alloc((size_t)CAP_SLOTS * 4);
    __bf16* wbufB = (__bf16*)alloc(wsz);               // only used on fused path
    const bool fused = (ws_size >= off);               // ~213 MB needed for fused

    // 1) x -> bf16; router; build
    conv_kernel<<<T_TOK * H_DIM / 1024, 256, 0, stream>>>(x, xb, T_TOK * H_DIM / 4);
    router_kernel<<<T_TOK / 4, 256, 0, stream>>>(x, gate_w, topi, topw);
    route_build_kernel<<<1, 64, 0, stream>>>(topi, topw, token_ids, token_w, tile_e, tile_k);

    const int nI4 = I_DIM * H_DIM / 4;
    const int nE4 = N_EXP * I_DIM * H_DIM / 4;
    const dim3 gSH(T_TOK / 128, I_DIM / 128), gSHd(T_TOK / 128, H_DIM / 128);
    const dim3 gRT(MAX_TILES, I_DIM / 128), gRTd(MAX_TILES, H_DIM / 128);

    if (fused) {
        // shared: gate+up fused -> down
        conv_kernel<<<nI4 / 256, 256, 0, stream>>>(shared_gate, wbufA, nI4);
        conv_kernel<<<nI4 / 256, 256, 0, stream>>>(shared_up, wbufB, nI4);
        gateup_fused<H_DIM><<<gSH, 256, 0, stream>>>(xb, wbufA, wbufB, hid, nullptr, nullptr);
        conv_kernel<<<nI4 / 256, 256, 0, stream>>>(shared_down, wbufA, nI4);
        gemm_k<2, I_DIM, H_DIM><<<gSHd, 256, 0, stream>>>(
            hid, wbufA, nullptr, out, nullptr, nullptr, nullptr, nullptr, 0);
        // routed: gate+up fused -> down k0/k1
        conv_kernel<<<nE4 / 256, 256, 0, stream>>>(expert_gate, wbufA, nE4);
        conv_kernel<<<nE4 / 256, 256, 0, stream>>>(expert_up, wbufB, nE4);
        gateup_fused<H_DIM><<<gRT, 256, 0, stream>>>(xb, wbufA, wbufB, hid, token_ids, tile_e);
        conv_kernel<<<nE4 / 256, 256, 0, stream>>>(expert_down, wbufA, nE4);
        gemm_k<3, I_DIM, H_DIM><<<gRTd, 256, 0, stream>>>(
            hid, wbufA, nullptr, out, token_ids, token_w, tile_e, tile_k, 0);
        gemm_k<3, I_DIM, H_DIM><<<gRTd, 256, 0, stream>>>(
            hid, wbufA, nullptr, out, token_ids, token_w, tile_e, tile_k, 1);
    } else {
        // R5-proven unfused sequence (single weight buffer)
        conv_kernel<<<nI4 / 256, 256, 0, stream>>>(shared_gate, wbufA, nI4);
        gemm_k<0, H_DIM, I_DIM><<<gSH, 256, 0, stream>>>(
            xb, wbufA, hid, nullptr, nullptr, nullptr, nullptr, nullptr, 0);
        conv_kernel<<<nI4 / 256, 256, 0, stream>>>(shared_up, wbufA, nI4);
        gemm_k<1, H_DIM, I_DIM><<<gSH, 256, 0, stream>>>(
            xb, wbufA, hid, nullptr, nullptr, nullptr, nullptr, nullptr, 0);
        conv_kernel<<<nI4 / 256, 256, 0, stream>>>(shared_down, wbufA, nI4);
        gemm_k<2, I_DIM, H_DIM><<<gSHd, 256, 0, stream>>>(
            hid, wbufA, nullptr, out, nullptr, nullptr, nullptr, nullptr, 0);
        conv_kernel<<<nE4 / 256, 256, 0, stream>>>(expert_gate, wbufA, nE4);
        gemm_k<0, H_DIM, I_DIM><<<gRT, 256, 0, stream>>>(
            xb, wbufA, hid, nullptr, token_ids, token_w, tile_e, tile_k, 0);
        conv_kernel<<<nE4 / 256, 256, 0, stream>>>(expert_up, wbufA, nE4);
        gemm_k<1, H_DIM, I_DIM><<<gRT, 256, 0, stream>>>(
            xb, wbufA, hid, nullptr, token_ids, token_w, tile_e, tile_k, 0);
        conv_kernel<<<nE4 / 256, 256, 0, stream>>>(expert_down, wbufA, nE4);
        gemm_k<3, I_DIM, H_DIM><<<gRTd, 256, 0, stream>>>(
            hid, wbufA, nullptr, out, token_ids, token_w, tile_e, tile_k, 0);
        gemm_k<3, I_DIM, H_DIM><<<gRTd, 256, 0, stream>>>(
            hid, wbufA, nullptr, out, token_ids, token_w, tile_e, tile_k, 1);
    }
}

// Round 8
// 929.612 us; speedup vs baseline: 1.2927x; 1.2927x over previous
//
#include <hip/hip_runtime.h>
#include <hip/hip_bf16.h>
#include <math.h>

#define T_TOK 8192
#define H_DIM 1024
#define I_DIM 2816
#define N_EXP 8
#define NREG  16           // (expert, k) regions
#define CAP_SLOTS 18432    // 2*T + 16*128 alignment headroom
#define MAX_TILES 144      // CAP_SLOTS / 128

typedef __bf16 bf16x8 __attribute__((ext_vector_type(8)));
typedef __bf16 bf16x4 __attribute__((ext_vector_type(4)));
typedef float f32x4 __attribute__((ext_vector_type(4)));

__device__ inline void gload_lds16(const void* g, void* l) {
    __builtin_amdgcn_global_load_lds((const __attribute__((address_space(1))) void*)g,
                                     (__attribute__((address_space(3))) void*)l, 16, 0, 0);
}

// Bijective XCD-aware tile swizzle (m204): same-XCD blocks get contiguous ids.
__device__ inline void swz_tile(int& bx, int& by) {
    const int nx = gridDim.x;
    const int nwg = nx * gridDim.y;
    int lin = by * nx + bx;
    int q = nwg >> 3, r = nwg & 7, xcd = lin & 7, pos = lin >> 3;
    int swz = (xcd < r ? xcd * (q + 1) : r * (q + 1) + (xcd - r) * q) + pos;
    bx = swz % nx; by = swz / nx;
}

// f32 -> bf16, 4 elems/thread
__global__ void conv_kernel(const float* __restrict__ src, __bf16* __restrict__ dst, int n4) {
    int i = blockIdx.x * 256 + threadIdx.x;
    if (i < n4) {
        float4 v = ((const float4*)src)[i];
        bf16x4 o;
        o[0] = (__bf16)v.x; o[1] = (__bf16)v.y; o[2] = (__bf16)v.z; o[3] = (__bf16)v.w;
        ((bf16x4*)dst)[i] = o;
    }
}

// One wave per token: logits over 8 experts (float4-vectorized), softmax, top-2.
// No global atomics (R4->R5: atomic cacheline ping-pong cost ~190us).
__global__ void router_kernel(const float* __restrict__ x, const float* __restrict__ gw,
                              int* __restrict__ topi, float* __restrict__ topw) {
    int t = blockIdx.x * 4 + (threadIdx.x >> 6);
    int lane = threadIdx.x & 63;
    if (t >= T_TOK) return;
    const float4* xr = (const float4*)(x + (size_t)t * H_DIM);
    float s[N_EXP];
#pragma unroll
    for (int e = 0; e < N_EXP; e++) s[e] = 0.0f;
#pragma unroll
    for (int j = 0; j < H_DIM / 256; ++j) {
        float4 xv = xr[j * 64 + lane];
#pragma unroll
        for (int e = 0; e < N_EXP; e++) {
            float4 gv = ((const float4*)(gw + (size_t)e * H_DIM))[j * 64 + lane];
            s[e] += xv.x * gv.x + xv.y * gv.y + xv.z * gv.z + xv.w * gv.w;
        }
    }
#pragma unroll
    for (int off = 32; off; off >>= 1) {
#pragma unroll
        for (int e = 0; e < N_EXP; e++) s[e] += __shfl_xor(s[e], off);
    }
    if (lane == 0) {
        float m = s[0];
#pragma unroll
        for (int e = 1; e < N_EXP; e++) m = fmaxf(m, s[e]);
        float p[N_EXP]; float sum = 0.0f;
#pragma unroll
        for (int e = 0; e < N_EXP; e++) { p[e] = expf(s[e] - m); sum += p[e]; }
#pragma unroll
        for (int e = 0; e < N_EXP; e++) p[e] /= sum;
        int i0 = 0;
#pragma unroll
        for (int e = 1; e < N_EXP; e++) if (p[e] > p[i0]) i0 = e;
        int i1 = (i0 == 0) ? 1 : 0;
#pragma unroll
        for (int e = 0; e < N_EXP; e++) if (e != i0 && p[e] > p[i1]) i1 = e;
        float rs = p[i0] + p[i1] + 1e-20f;
        topi[t * 2 + 0] = i0; topi[t * 2 + 1] = i1;
        topw[t * 2 + 0] = p[i0] / rs; topw[t * 2 + 1] = p[i1] / rs;
    }
}

// Single-wave routing build: histogram -> bases -> tile tables -> slot assignment.
__global__ void route_build_kernel(const int* __restrict__ topi, const float* __restrict__ topw,
                                   int* __restrict__ token_ids, float* __restrict__ token_w,
                                   int* __restrict__ tile_e, int* __restrict__ tile_k) {
    __shared__ int h[64][NREG];
    __shared__ int bases[NREG];
    __shared__ int cur[64][NREG];
    const int lane = threadIdx.x;   // 0..63, single wave

    for (int i = lane; i < CAP_SLOTS; i += 64) token_ids[i] = -1;

#pragma unroll
    for (int r = 0; r < NREG; r++) h[lane][r] = 0;
    for (int i = 0; i < T_TOK * 2 / 64; i++) {
        int entry = i * 64 + lane;
        int r = topi[entry] * 2 + (entry & 1);
        h[lane][r]++;
    }
    __syncthreads();

    if (lane < NREG) {
        int c = 0;
        for (int l = 0; l < 64; l++) c += h[l][lane];
        bases[lane] = c;
    }
    __syncthreads();

    if (lane == 0) {
        int b = 0, t = 0;
        for (int r = 0; r < NREG; r++) {
            int c = bases[r];
            int nt = (c + 127) >> 7;
            bases[r] = b;
            for (int i = 0; i < nt; i++) { tile_e[t] = r >> 1; tile_k[t] = r & 1; t++; }
            b += nt << 7;
        }
        for (; t < MAX_TILES; t++) { tile_e[t] = -1; tile_k[t] = -1; }
    }
    __syncthreads();

    for (int r = 0; r < NREG; r++) {
        int s = bases[r];
        for (int l = 0; l < lane; l++) s += h[l][r];
        cur[lane][r] = s;
    }
    __syncthreads();

    for (int i = 0; i < T_TOK * 2 / 64; i++) {
        int entry = i * 64 + lane;
        int r = topi[entry] * 2 + (entry & 1);
        int slot = cur[lane][r]++;
        token_ids[slot] = entry >> 1;
        token_w[slot] = topw[entry];
    }
}

// Fused gate+up GEMM: 128x128 tile, BK=32, 4 waves, A staged once, both B's via
// gload_lds. hid = silu(A@Wg^T) * (A@Wu^T), written once (no RMW re-read).
// launch_bounds(256,2): needs ~210 unified VGPR+AGPR/thread; (256,3) spilled
// accumulators -> 782 MB scratch writes in R6.
template<int K>
__global__ __launch_bounds__(256, 2)
void gateup_fused(const __bf16* __restrict__ A,
                  const __bf16* __restrict__ Wg, const __bf16* __restrict__ Wu,
                  __bf16* __restrict__ hid,
                  const int* __restrict__ token_ids, const int* __restrict__ tile_e) {
    int bx = blockIdx.x, by = blockIdx.y;
    swz_tile(bx, by);
    int e = 0;
    if (tile_e) { e = tile_e[bx]; if (e < 0) return; }
    const int m0 = bx * 128, n0 = by * 128;

    __shared__ __bf16 As[2][128 * 32];
    __shared__ __bf16 Bg[2][128 * 32];
    __shared__ __bf16 Bu[2][128 * 32];

    const int tid = threadIdx.x, lane = tid & 63, wid = tid >> 6;
    const int wm = wid >> 1, wn = wid & 1;

    const int srow = wid * 16 + (lane >> 2);
    const int colb = (lane & 3) * 16;

    int ar0, ar1;
    if (tile_e) {
        int t0 = token_ids[m0 + srow], t1 = token_ids[m0 + srow + 64];
        ar0 = t0 < 0 ? 0 : t0;
        ar1 = t1 < 0 ? 0 : t1;
    } else {
        ar0 = m0 + srow; ar1 = m0 + srow + 64;
    }
    const char* pA0 = (const char*)A + (size_t)ar0 * (K * 2) + colb;
    const char* pA1 = (const char*)A + (size_t)ar1 * (K * 2) + colb;
    const char* pG0 = (const char*)Wg + ((size_t)e * I_DIM + n0 + srow) * (K * 2) + colb;
    const char* pG1 = pG0 + (size_t)64 * (K * 2);
    const char* pU0 = (const char*)Wu + ((size_t)e * I_DIM + n0 + srow) * (K * 2) + colb;
    const char* pU1 = pU0 + (size_t)64 * (K * 2);
    const int ldsoff = wid * 1024;

    f32x4 accg[4][4], accu[4][4];
    const f32x4 z4 = {0.f, 0.f, 0.f, 0.f};
#pragma unroll
    for (int i = 0; i < 4; i++)
#pragma unroll
        for (int j = 0; j < 4; j++) { accg[i][j] = z4; accu[i][j] = z4; }

    constexpr int NT = K / 32;

    auto stage = [&](int buf, int kt) {
        const size_t ko = (size_t)kt * 64;
        char* a_l = (char*)As[buf] + ldsoff;
        gload_lds16(pA0 + ko, a_l);
        gload_lds16(pA1 + ko, a_l + 4096);
        char* g_l = (char*)Bg[buf] + ldsoff;
        gload_lds16(pG0 + ko, g_l);
        gload_lds16(pG1 + ko, g_l + 4096);
        char* u_l = (char*)Bu[buf] + ldsoff;
        gload_lds16(pU0 + ko, u_l);
        gload_lds16(pU1 + ko, u_l + 4096);
    };

    auto compute = [&](int buf) {
        const int rA = wm * 64 + (lane & 15);
        const int rB = wn * 64 + (lane & 15);
        const int cK = (lane >> 4) * 8;
        bf16x8 a[4], g[4], u[4];
#pragma unroll
        for (int i = 0; i < 4; i++) a[i] = *(const bf16x8*)&As[buf][(rA + i * 16) * 32 + cK];
#pragma unroll
        for (int j = 0; j < 4; j++) {
            g[j] = *(const bf16x8*)&Bg[buf][(rB + j * 16) * 32 + cK];
            u[j] = *(const bf16x8*)&Bu[buf][(rB + j * 16) * 32 + cK];
        }
#pragma unroll
        for (int i = 0; i < 4; i++)
#pragma unroll
            for (int j = 0; j < 4; j++) {
                accg[i][j] = __builtin_amdgcn_mfma_f32_16x16x32_bf16(a[i], g[j], accg[i][j], 0, 0, 0);
                accu[i][j] = __builtin_amdgcn_mfma_f32_16x16x32_bf16(a[i], u[j], accu[i][j], 0, 0, 0);
            }
    };

    stage(0, 0);
    __syncthreads();
    int cur = 0;
    for (int kt = 0; kt < NT; ++kt) {
        if (kt + 1 < NT) stage(cur ^ 1, kt + 1);
        compute(cur);
        __syncthreads();
        cur ^= 1;
    }

    const int cb = lane & 15, rb = (lane >> 4) * 4;
#pragma unroll
    for (int i = 0; i < 4; i++)
#pragma unroll
        for (int j = 0; j < 4; j++)
#pragma unroll
            for (int r = 0; r < 4; r++) {
                const int row = wm * 64 + i * 16 + rb + r;
                const int col = n0 + wn * 64 + j * 16 + cb;
                float gv = accg[i][j][r];
                float uv = accu[i][j][r];
                float h = (gv / (1.0f + __expf(-gv))) * uv;
                hid[(size_t)(m0 + row) * I_DIM + col] = (__bf16)h;
            }
}

// m97-shape GEMM (R5-proven), with XCD swizzle.
// EPI: 0=gate(silu->hid) 1=up(hid*=v) 2=down_shared(out=v) 3=down_routed(out[tok]+=w*v)
template<int EPI, int KDIM, int NBROWS>
__global__ __launch_bounds__(256, 4)
void gemm_k(const __bf16* __restrict__ A, const __bf16* __restrict__ B,
            __bf16* __restrict__ hid, float* __restrict__ out,
            const int* __restrict__ token_ids, const float* __restrict__ token_w,
            const int* __restrict__ tile_e, const int* __restrict__ tile_k, int ksel) {
    int bx = blockIdx.x, by = blockIdx.y;
    swz_tile(bx, by);
    int e = 0;
    if (tile_e) {
        e = tile_e[bx];
        if (e < 0) return;
        if (EPI == 3 && tile_k[bx] != ksel) return;
    }
    const int m0 = bx * 128, n0 = by * 128;

    __shared__ __bf16 As[2][128 * 32];
    __shared__ __bf16 Bs[2][128 * 32];

    const int tid = threadIdx.x, lane = tid & 63, wid = tid >> 6;
    const int wm = wid >> 1, wn = wid & 1;

    const int srow = wid * 16 + (lane >> 2);
    const int colb = (lane & 3) * 16;

    int ar0, ar1;
    if (EPI <= 1 && token_ids) {
        int t0 = token_ids[m0 + srow], t1 = token_ids[m0 + srow + 64];
        ar0 = t0 < 0 ? 0 : t0;
        ar1 = t1 < 0 ? 0 : t1;
    } else {
        ar0 = m0 + srow; ar1 = m0 + srow + 64;
    }
    const char* pA0 = (const char*)A + (size_t)ar0 * (KDIM * 2) + colb;
    const char* pA1 = (const char*)A + (size_t)ar1 * (KDIM * 2) + colb;
    const char* pB0 = (const char*)B + ((size_t)e * NBROWS + n0 + srow) * (KDIM * 2) + colb;
    const char* pB1 = pB0 + (size_t)64 * (KDIM * 2);
    const int ldsoff = wid * 1024;

    f32x4 acc[4][4];
    const f32x4 z4 = {0.f, 0.f, 0.f, 0.f};
#pragma unroll
    for (int i = 0; i < 4; i++)
#pragma unroll
        for (int j = 0; j < 4; j++) acc[i][j] = z4;

    constexpr int NT = KDIM / 32;

    auto stage = [&](int buf, int kt) {
        const size_t ko = (size_t)kt * 64;
        char* a_l = (char*)As[buf] + ldsoff;
        gload_lds16(pA0 + ko, a_l);
        gload_lds16(pA1 + ko, a_l + 4096);
        char* b_l = (char*)Bs[buf] + ldsoff;
        gload_lds16(pB0 + ko, b_l);
        gload_lds16(pB1 + ko, b_l + 4096);
    };

    auto compute = [&](int buf) {
        const int rA = wm * 64 + (lane & 15);
        const int rB = wn * 64 + (lane & 15);
        const int cK = (lane >> 4) * 8;
        bf16x8 a[4], b[4];
#pragma unroll
        for (int i = 0; i < 4; i++) a[i] = *(const bf16x8*)&As[buf][(rA + i * 16) * 32 + cK];
#pragma unroll
        for (int j = 0; j < 4; j++) b[j] = *(const bf16x8*)&Bs[buf][(rB + j * 16) * 32 + cK];
#pragma unroll
        for (int i = 0; i < 4; i++)
#pragma unroll
            for (int j = 0; j < 4; j++)
                acc[i][j] = __builtin_amdgcn_mfma_f32_16x16x32_bf16(a[i], b[j], acc[i][j], 0, 0, 0);
    };

    stage(0, 0);
    __syncthreads();
    int cur = 0;
    for (int kt = 0; kt < NT; ++kt) {
        if (kt + 1 < NT) stage(cur ^ 1, kt + 1);
        compute(cur);
        __syncthreads();
        cur ^= 1;
    }

    const int cb = lane & 15, rb = (lane >> 4) * 4;
#pragma unroll
    for (int i = 0; i < 4; i++)
#pragma unroll
        for (int j = 0; j < 4; j++)
#pragma unroll
            for (int r = 0; r < 4; r++) {
                const int row = wm * 64 + i * 16 + rb + r;
                const int col = n0 + wn * 64 + j * 16 + cb;
                float v = acc[i][j][r];
                if (EPI == 0) {
                    float sv = v / (1.0f + __expf(-v));
                    hid[(size_t)(m0 + row) * NBROWS + col] = (__bf16)sv;
                } else if (EPI == 1) {
                    size_t idx = (size_t)(m0 + row) * NBROWS + col;
                    hid[idx] = (__bf16)((float)hid[idx] * v);
                } else if (EPI == 2) {
                    out[(size_t)(m0 + row) * H_DIM + col] = v;
                } else {
                    int slot = m0 + row;
                    int tok = token_ids[slot];
                    if (tok >= 0) {
                        size_t o = (size_t)tok * H_DIM + col;
                        out[o] += token_w[slot] * v;   // k-split: no same-token race
                    }
                }
            }
}

extern "C" void kernel_launch(void* const* d_in, const int* in_sizes, int n_in,
                              void* d_out, int out_size, void* d_ws, size_t ws_size,
                              hipStream_t stream) {
    const float* x = (const float*)d_in[0];
    const float* gate_w = (const float*)d_in[1];
    const float* expert_gate = (const float*)d_in[2];
    const float* expert_up = (const float*)d_in[3];
    const float* expert_down = (const float*)d_in[4];
    const float* shared_gate = (const float*)d_in[5];
    const float* shared_up = (const float*)d_in[6];
    const float* shared_down = (const float*)d_in[7];
    float* out = (float*)d_out;

    char* w = (char*)d_ws;
    size_t off = 0;
    auto alloc = [&](size_t bytes) {
        void* p = w + off;
        off = (off + bytes + 255) & ~(size_t)255;
        return p;
    };

    const size_t wsz = (size_t)N_EXP * I_DIM * H_DIM * 2;   // 46.1 MB
    __bf16* xb = (__bf16*)alloc((size_t)T_TOK * H_DIM * 2);
    __bf16* wbufA = (__bf16*)alloc(wsz);
    __bf16* hid = (__bf16*)alloc((size_t)CAP_SLOTS * I_DIM * 2);
    int* topi = (int*)alloc((size_t)T_TOK * 2 * 4);
    float* topw = (float*)alloc((size_t)T_TOK * 2 * 4);
    int* tile_e = (int*)alloc(MAX_TILES * 4);
    int* tile_k = (int*)alloc(MAX_TILES * 4);
    int* token_ids = (int*)alloc((size_t)CAP_SLOTS * 4);
    float* token_w = (float*)alloc((size_t)CAP_SLOTS * 4);
    __bf16* wbufB = (__bf16*)alloc(wsz);               // only used on fused path
    const bool fused = (ws_size >= off);               // ~213 MB needed for fused

    // 1) x -> bf16; router; build
    conv_kernel<<<T_TOK * H_DIM / 1024, 256, 0, stream>>>(x, xb, T_TOK * H_DIM / 4);
    router_kernel<<<T_TOK / 4, 256, 0, stream>>>(x, gate_w, topi, topw);
    route_build_kernel<<<1, 64, 0, stream>>>(topi, topw, token_ids, token_w, tile_e, tile_k);

    const int nI4 = I_DIM * H_DIM / 4;
    const int nE4 = N_EXP * I_DIM * H_DIM / 4;
    const dim3 gSH(T_TOK / 128, I_DIM / 128), gSHd(T_TOK / 128, H_DIM / 128);
    const dim3 gRT(MAX_TILES, I_DIM / 128), gRTd(MAX_TILES, H_DIM / 128);

    if (fused) {
        // shared: gate+up fused -> down
        conv_kernel<<<nI4 / 256, 256, 0, stream>>>(shared_gate, wbufA, nI4);
        conv_kernel<<<nI4 / 256, 256, 0, stream>>>(shared_up, wbufB, nI4);
        gateup_fused<H_DIM><<<gSH, 256, 0, stream>>>(xb, wbufA, wbufB, hid, nullptr, nullptr);
        conv_kernel<<<nI4 / 256, 256, 0, stream>>>(shared_down, wbufA, nI4);
        gemm_k<2, I_DIM, H_DIM><<<gSHd, 256, 0, stream>>>(
            hid, wbufA, nullptr, out, nullptr, nullptr, nullptr, nullptr, 0);
        // routed: gate+up fused -> down k0/k1
        conv_kernel<<<nE4 / 256, 256, 0, stream>>>(expert_gate, wbufA, nE4);
        conv_kernel<<<nE4 / 256, 256, 0, stream>>>(expert_up, wbufB, nE4);
        gateup_fused<H_DIM><<<gRT, 256, 0, stream>>>(xb, wbufA, wbufB, hid, token_ids, tile_e);
        conv_kernel<<<nE4 / 256, 256, 0, stream>>>(expert_down, wbufA, nE4);
        gemm_k<3, I_DIM, H_DIM><<<gRTd, 256, 0, stream>>>(
            hid, wbufA, nullptr, out, token_ids, token_w, tile_e, tile_k, 0);
        gemm_k<3, I_DIM, H_DIM><<<gRTd, 256, 0, stream>>>(
            hid, wbufA, nullptr, out, token_ids, token_w, tile_e, tile_k, 1);
    } else {
        // R5-proven unfused sequence (single weight buffer)
        conv_kernel<<<nI4 / 256, 256, 0, stream>>>(shared_gate, wbufA, nI4);
        gemm_k<0, H_DIM, I_DIM><<<gSH, 256, 0, stream>>>(
            xb, wbufA, hid, nullptr, nullptr, nullptr, nullptr, nullptr, 0);
        conv_kernel<<<nI4 / 256, 256, 0, stream>>>(shared_up, wbufA, nI4);
        gemm_k<1, H_DIM, I_DIM><<<gSH, 256, 0, stream>>>(
            xb, wbufA, hid, nullptr, nullptr, nullptr, nullptr, nullptr, 0);
        conv_kernel<<<nI4 / 256, 256, 0, stream>>>(shared_down, wbufA, nI4);
        gemm_k<2, I_DIM, H_DIM><<<gSHd, 256, 0, stream>>>(
            hid, wbufA, nullptr, out, nullptr, nullptr, nullptr, nullptr, 0);
        conv_kernel<<<nE4 / 256, 256, 0, stream>>>(expert_gate, wbufA, nE4);
        gemm_k<0, H_DIM, I_DIM><<<gRT, 256, 0, stream>>>(
            xb, wbufA, hid, nullptr, token_ids, token_w, tile_e, tile_k, 0);
        conv_kernel<<<nE4 / 256, 256, 0, stream>>>(expert_up, wbufA, nE4);
        gemm_k<1, H_DIM, I_DIM><<<gRT, 256, 0, stream>>>(
            xb, wbufA, hid, nullptr, token_ids, token_w, tile_e, tile_k, 0);
        conv_kernel<<<nE4 / 256, 256, 0, stream>>>(expert_down, wbufA, nE4);
        gemm_k<3, I_DIM, H_DIM><<<gRTd, 256, 0, stream>>>(
            hid, wbufA, nullptr, out, token_ids, token_w, tile_e, tile_k, 0);
        gemm_k<3, I_DIM, H_DIM><<<gRTd, 256, 0, stream>>>(
            hid, wbufA, nullptr, out, token_ids, token_w, tile_e, tile_k, 1);
    }
}

// Round 9
// 877.965 us; speedup vs baseline: 1.3688x; 1.0588x over previous
//
#include <hip/hip_runtime.h>
#include <hip/hip_bf16.h>
#include <math.h>

#define T_TOK 8192
#define H_DIM 1024
#define I_DIM 2816
#define N_EXP 8
#define NREG  16           // (expert, k) regions
#define CAP_SLOTS 18432    // 2*T + 16*128 alignment headroom
#define MAX_TILES 144      // CAP_SLOTS / 128

typedef __bf16 bf16x8 __attribute__((ext_vector_type(8)));
typedef __bf16 bf16x4 __attribute__((ext_vector_type(4)));
typedef float f32x4 __attribute__((ext_vector_type(4)));

__device__ inline void gload_lds16(const void* g, void* l) {
    __builtin_amdgcn_global_load_lds((const __attribute__((address_space(1))) void*)g,
                                     (__attribute__((address_space(3))) void*)l, 16, 0, 0);
}

// Bijective XCD-aware tile swizzle (m204): same-XCD blocks get contiguous ids.
__device__ inline void swz_tile(int& bx, int& by) {
    const int nx = gridDim.x;
    const int nwg = nx * gridDim.y;
    int lin = by * nx + bx;
    int q = nwg >> 3, r = nwg & 7, xcd = lin & 7, pos = lin >> 3;
    int swz = (xcd < r ? xcd * (q + 1) : r * (q + 1) + (xcd - r) * q) + pos;
    bx = swz % nx; by = swz / nx;
}

// f32 -> bf16, 4 elems/thread
__global__ void conv_kernel(const float* __restrict__ src, __bf16* __restrict__ dst, int n4) {
    int i = blockIdx.x * 256 + threadIdx.x;
    if (i < n4) {
        float4 v = ((const float4*)src)[i];
        bf16x4 o;
        o[0] = (__bf16)v.x; o[1] = (__bf16)v.y; o[2] = (__bf16)v.z; o[3] = (__bf16)v.w;
        ((bf16x4*)dst)[i] = o;
    }
}

// One wave per token: logits over 8 experts (float4-vectorized), softmax, top-2.
// No global atomics (R4->R5: atomic cacheline ping-pong cost ~190us).
__global__ void router_kernel(const float* __restrict__ x, const float* __restrict__ gw,
                              int* __restrict__ topi, float* __restrict__ topw) {
    int t = blockIdx.x * 4 + (threadIdx.x >> 6);
    int lane = threadIdx.x & 63;
    if (t >= T_TOK) return;
    const float4* xr = (const float4*)(x + (size_t)t * H_DIM);
    float s[N_EXP];
#pragma unroll
    for (int e = 0; e < N_EXP; e++) s[e] = 0.0f;
#pragma unroll
    for (int j = 0; j < H_DIM / 256; ++j) {
        float4 xv = xr[j * 64 + lane];
#pragma unroll
        for (int e = 0; e < N_EXP; e++) {
            float4 gv = ((const float4*)(gw + (size_t)e * H_DIM))[j * 64 + lane];
            s[e] += xv.x * gv.x + xv.y * gv.y + xv.z * gv.z + xv.w * gv.w;
        }
    }
#pragma unroll
    for (int off = 32; off; off >>= 1) {
#pragma unroll
        for (int e = 0; e < N_EXP; e++) s[e] += __shfl_xor(s[e], off);
    }
    if (lane == 0) {
        float m = s[0];
#pragma unroll
        for (int e = 1; e < N_EXP; e++) m = fmaxf(m, s[e]);
        float p[N_EXP]; float sum = 0.0f;
#pragma unroll
        for (int e = 0; e < N_EXP; e++) { p[e] = expf(s[e] - m); sum += p[e]; }
#pragma unroll
        for (int e = 0; e < N_EXP; e++) p[e] /= sum;
        int i0 = 0;
#pragma unroll
        for (int e = 1; e < N_EXP; e++) if (p[e] > p[i0]) i0 = e;
        int i1 = (i0 == 0) ? 1 : 0;
#pragma unroll
        for (int e = 0; e < N_EXP; e++) if (e != i0 && p[e] > p[i1]) i1 = e;
        float rs = p[i0] + p[i1] + 1e-20f;
        topi[t * 2 + 0] = i0; topi[t * 2 + 1] = i1;
        topw[t * 2 + 0] = p[i0] / rs; topw[t * 2 + 1] = p[i1] / rs;
    }
}

// Single-wave routing build: histogram -> bases -> tile tables -> slot assignment.
__global__ void route_build_kernel(const int* __restrict__ topi, const float* __restrict__ topw,
                                   int* __restrict__ token_ids, float* __restrict__ token_w,
                                   int* __restrict__ tile_e, int* __restrict__ tile_k) {
    __shared__ int h[64][NREG];
    __shared__ int bases[NREG];
    __shared__ int cur[64][NREG];
    const int lane = threadIdx.x;   // 0..63, single wave

    for (int i = lane; i < CAP_SLOTS; i += 64) token_ids[i] = -1;

#pragma unroll
    for (int r = 0; r < NREG; r++) h[lane][r] = 0;
    for (int i = 0; i < T_TOK * 2 / 64; i++) {
        int entry = i * 64 + lane;
        int r = topi[entry] * 2 + (entry & 1);
        h[lane][r]++;
    }
    __syncthreads();

    if (lane < NREG) {
        int c = 0;
        for (int l = 0; l < 64; l++) c += h[l][lane];
        bases[lane] = c;
    }
    __syncthreads();

    if (lane == 0) {
        int b = 0, t = 0;
        for (int r = 0; r < NREG; r++) {
            int c = bases[r];
            int nt = (c + 127) >> 7;
            bases[r] = b;
            for (int i = 0; i < nt; i++) { tile_e[t] = r >> 1; tile_k[t] = r & 1; t++; }
            b += nt << 7;
        }
        for (; t < MAX_TILES; t++) { tile_e[t] = -1; tile_k[t] = -1; }
    }
    __syncthreads();

    for (int r = 0; r < NREG; r++) {
        int s = bases[r];
        for (int l = 0; l < lane; l++) s += h[l][r];
        cur[lane][r] = s;
    }
    __syncthreads();

    for (int i = 0; i < T_TOK * 2 / 64; i++) {
        int entry = i * 64 + lane;
        int r = topi[entry] * 2 + (entry & 1);
        int slot = cur[lane][r]++;
        token_ids[slot] = entry >> 1;
        token_w[slot] = topw[entry];
    }
}

// Fused gate+up GEMM: 128x128 tile, BK=32, 8 waves (512 thr), each wave owns a
// 64x32 slab of BOTH gate and up (acc = 64 VGPR, total ~130 -> 3 waves/EU vs
// R7's 2). A staged once; hid = silu(A@Wg^T)*(A@Wu^T) written once.
template<int K>
__global__ __launch_bounds__(512, 3)
void gateup_fused(const __bf16* __restrict__ A,
                  const __bf16* __restrict__ Wg, const __bf16* __restrict__ Wu,
                  __bf16* __restrict__ hid,
                  const int* __restrict__ token_ids, const int* __restrict__ tile_e) {
    int bx = blockIdx.x, by = blockIdx.y;
    swz_tile(bx, by);
    int e = 0;
    if (tile_e) { e = tile_e[bx]; if (e < 0) return; }
    const int m0 = bx * 128, n0 = by * 128;

    __shared__ __bf16 As[2][128 * 32];
    __shared__ __bf16 Bg[2][128 * 32];
    __shared__ __bf16 Bu[2][128 * 32];

    const int tid = threadIdx.x, lane = tid & 63, wid = tid >> 6;  // wid 0..7
    const int wm = wid >> 2, wn = wid & 3;    // 2 x 4 waves over 128x128

    // staging: thread t covers LDS bytes [t*16, t*16+16): row = t>>2, colb = (t&3)*16
    const int srow = tid >> 2;
    const int colb = (tid & 3) * 16;

    int ar;
    if (tile_e) {
        int t0 = token_ids[m0 + srow];
        ar = t0 < 0 ? 0 : t0;
    } else {
        ar = m0 + srow;
    }
    const char* pA = (const char*)A + (size_t)ar * (K * 2) + colb;
    const char* pG = (const char*)Wg + ((size_t)e * I_DIM + n0 + srow) * (K * 2) + colb;
    const char* pU = (const char*)Wu + ((size_t)e * I_DIM + n0 + srow) * (K * 2) + colb;
    const int ldsoff = wid * 1024;   // bytes; lane writes ldsoff + lane*16 = tid*16

    f32x4 accg[4][2], accu[4][2];
    const f32x4 z4 = {0.f, 0.f, 0.f, 0.f};
#pragma unroll
    for (int i = 0; i < 4; i++)
#pragma unroll
        for (int j = 0; j < 2; j++) { accg[i][j] = z4; accu[i][j] = z4; }

    constexpr int NT = K / 32;

    auto stage = [&](int buf, int kt) {
        const size_t ko = (size_t)kt * 64;   // BK=32 bf16 = 64 bytes
        gload_lds16(pA + ko, (char*)As[buf] + ldsoff);
        gload_lds16(pG + ko, (char*)Bg[buf] + ldsoff);
        gload_lds16(pU + ko, (char*)Bu[buf] + ldsoff);
    };

    auto compute = [&](int buf) {
        const int rA = wm * 64 + (lane & 15);
        const int rB = wn * 32 + (lane & 15);
        const int cK = (lane >> 4) * 8;
        bf16x8 a[4], g[2], u[2];
#pragma unroll
        for (int i = 0; i < 4; i++) a[i] = *(const bf16x8*)&As[buf][(rA + i * 16) * 32 + cK];
#pragma unroll
        for (int j = 0; j < 2; j++) {
            g[j] = *(const bf16x8*)&Bg[buf][(rB + j * 16) * 32 + cK];
            u[j] = *(const bf16x8*)&Bu[buf][(rB + j * 16) * 32 + cK];
        }
#pragma unroll
        for (int i = 0; i < 4; i++)
#pragma unroll
            for (int j = 0; j < 2; j++) {
                accg[i][j] = __builtin_amdgcn_mfma_f32_16x16x32_bf16(a[i], g[j], accg[i][j], 0, 0, 0);
                accu[i][j] = __builtin_amdgcn_mfma_f32_16x16x32_bf16(a[i], u[j], accu[i][j], 0, 0, 0);
            }
    };

    stage(0, 0);
    __syncthreads();
    int cur = 0;
    for (int kt = 0; kt < NT; ++kt) {
        if (kt + 1 < NT) stage(cur ^ 1, kt + 1);
        compute(cur);
        __syncthreads();
        cur ^= 1;
    }

    const int cb = lane & 15, rb = (lane >> 4) * 4;
#pragma unroll
    for (int i = 0; i < 4; i++)
#pragma unroll
        for (int j = 0; j < 2; j++)
#pragma unroll
            for (int r = 0; r < 4; r++) {
                const int row = wm * 64 + i * 16 + rb + r;
                const int col = n0 + wn * 32 + j * 16 + cb;
                float gv = accg[i][j][r];
                float uv = accu[i][j][r];
                float h = (gv / (1.0f + __expf(-gv))) * uv;
                hid[(size_t)(m0 + row) * I_DIM + col] = (__bf16)h;
            }
}

// m97-shape GEMM (R5-proven), with XCD swizzle.
// EPI: 0=gate(silu->hid) 1=up(hid*=v) 2=down_shared(out=v) 3=down_routed(out[tok]+=w*v)
template<int EPI, int KDIM, int NBROWS>
__global__ __launch_bounds__(256, 4)
void gemm_k(const __bf16* __restrict__ A, const __bf16* __restrict__ B,
            __bf16* __restrict__ hid, float* __restrict__ out,
            const int* __restrict__ token_ids, const float* __restrict__ token_w,
            const int* __restrict__ tile_e, const int* __restrict__ tile_k, int ksel) {
    int bx = blockIdx.x, by = blockIdx.y;
    swz_tile(bx, by);
    int e = 0;
    if (tile_e) {
        e = tile_e[bx];
        if (e < 0) return;
        if (EPI == 3 && tile_k[bx] != ksel) return;
    }
    const int m0 = bx * 128, n0 = by * 128;

    __shared__ __bf16 As[2][128 * 32];
    __shared__ __bf16 Bs[2][128 * 32];

    const int tid = threadIdx.x, lane = tid & 63, wid = tid >> 6;
    const int wm = wid >> 1, wn = wid & 1;

    const int srow = wid * 16 + (lane >> 2);
    const int colb = (lane & 3) * 16;

    int ar0, ar1;
    if (EPI <= 1 && token_ids) {
        int t0 = token_ids[m0 + srow], t1 = token_ids[m0 + srow + 64];
        ar0 = t0 < 0 ? 0 : t0;
        ar1 = t1 < 0 ? 0 : t1;
    } else {
        ar0 = m0 + srow; ar1 = m0 + srow + 64;
    }
    const char* pA0 = (const char*)A + (size_t)ar0 * (KDIM * 2) + colb;
    const char* pA1 = (const char*)A + (size_t)ar1 * (KDIM * 2) + colb;
    const char* pB0 = (const char*)B + ((size_t)e * NBROWS + n0 + srow) * (KDIM * 2) + colb;
    const char* pB1 = pB0 + (size_t)64 * (KDIM * 2);
    const int ldsoff = wid * 1024;

    f32x4 acc[4][4];
    const f32x4 z4 = {0.f, 0.f, 0.f, 0.f};
#pragma unroll
    for (int i = 0; i < 4; i++)
#pragma unroll
        for (int j = 0; j < 4; j++) acc[i][j] = z4;

    constexpr int NT = KDIM / 32;

    auto stage = [&](int buf, int kt) {
        const size_t ko = (size_t)kt * 64;
        char* a_l = (char*)As[buf] + ldsoff;
        gload_lds16(pA0 + ko, a_l);
        gload_lds16(pA1 + ko, a_l + 4096);
        char* b_l = (char*)Bs[buf] + ldsoff;
        gload_lds16(pB0 + ko, b_l);
        gload_lds16(pB1 + ko, b_l + 4096);
    };

    auto compute = [&](int buf) {
        const int rA = wm * 64 + (lane & 15);
        const int rB = wn * 64 + (lane & 15);
        const int cK = (lane >> 4) * 8;
        bf16x8 a[4], b[4];
#pragma unroll
        for (int i = 0; i < 4; i++) a[i] = *(const bf16x8*)&As[buf][(rA + i * 16) * 32 + cK];
#pragma unroll
        for (int j = 0; j < 4; j++) b[j] = *(const bf16x8*)&Bs[buf][(rB + j * 16) * 32 + cK];
#pragma unroll
        for (int i = 0; i < 4; i++)
#pragma unroll
            for (int j = 0; j < 4; j++)
                acc[i][j] = __builtin_amdgcn_mfma_f32_16x16x32_bf16(a[i], b[j], acc[i][j], 0, 0, 0);
    };

    stage(0, 0);
    __syncthreads();
    int cur = 0;
    for (int kt = 0; kt < NT; ++kt) {
        if (kt + 1 < NT) stage(cur ^ 1, kt + 1);
        compute(cur);
        __syncthreads();
        cur ^= 1;
    }

    const int cb = lane & 15, rb = (lane >> 4) * 4;
#pragma unroll
    for (int i = 0; i < 4; i++)
#pragma unroll
        for (int j = 0; j < 4; j++)
#pragma unroll
            for (int r = 0; r < 4; r++) {
                const int row = wm * 64 + i * 16 + rb + r;
                const int col = n0 + wn * 64 + j * 16 + cb;
                float v = acc[i][j][r];
                if (EPI == 0) {
                    float sv = v / (1.0f + __expf(-v));
                    hid[(size_t)(m0 + row) * NBROWS + col] = (__bf16)sv;
                } else if (EPI == 1) {
                    size_t idx = (size_t)(m0 + row) * NBROWS + col;
                    hid[idx] = (__bf16)((float)hid[idx] * v);
                } else if (EPI == 2) {
                    out[(size_t)(m0 + row) * H_DIM + col] = v;
                } else {
                    int slot = m0 + row;
                    int tok = token_ids[slot];
                    if (tok >= 0) {
                        size_t o = (size_t)tok * H_DIM + col;
                        out[o] += token_w[slot] * v;   // k-split: no same-token race
                    }
                }
            }
}

extern "C" void kernel_launch(void* const* d_in, const int* in_sizes, int n_in,
                              void* d_out, int out_size, void* d_ws, size_t ws_size,
                              hipStream_t stream) {
    const float* x = (const float*)d_in[0];
    const float* gate_w = (const float*)d_in[1];
    const float* expert_gate = (const float*)d_in[2];
    const float* expert_up = (const float*)d_in[3];
    const float* expert_down = (const float*)d_in[4];
    const float* shared_gate = (const float*)d_in[5];
    const float* shared_up = (const float*)d_in[6];
    const float* shared_down = (const float*)d_in[7];
    float* out = (float*)d_out;

    char* w = (char*)d_ws;
    size_t off = 0;
    auto alloc = [&](size_t bytes) {
        void* p = w + off;
        off = (off + bytes + 255) & ~(size_t)255;
        return p;
    };

    const size_t wsz = (size_t)N_EXP * I_DIM * H_DIM * 2;   // 46.1 MB
    __bf16* xb = (__bf16*)alloc((size_t)T_TOK * H_DIM * 2);
    __bf16* wbufA = (__bf16*)alloc(wsz);
    __bf16* hid = (__bf16*)alloc((size_t)CAP_SLOTS * I_DIM * 2);
    int* topi = (int*)alloc((size_t)T_TOK * 2 * 4);
    float* topw = (float*)alloc((size_t)T_TOK * 2 * 4);
    int* tile_e = (int*)alloc(MAX_TILES * 4);
    int* tile_k = (int*)alloc(MAX_TILES * 4);
    int* token_ids = (int*)alloc((size_t)CAP_SLOTS * 4);
    float* token_w = (float*)alloc((size_t)CAP_SLOTS * 4);
    __bf16* wbufB = (__bf16*)alloc(wsz);               // only used on fused path
    const bool fused = (ws_size >= off);               // ~213 MB needed for fused

    // 1) x -> bf16; router; build
    conv_kernel<<<T_TOK * H_DIM / 1024, 256, 0, stream>>>(x, xb, T_TOK * H_DIM / 4);
    router_kernel<<<T_TOK / 4, 256, 0, stream>>>(x, gate_w, topi, topw);
    route_build_kernel<<<1, 64, 0, stream>>>(topi, topw, token_ids, token_w, tile_e, tile_k);

    const int nI4 = I_DIM * H_DIM / 4;
    const int nE4 = N_EXP * I_DIM * H_DIM / 4;
    const dim3 gSH(T_TOK / 128, I_DIM / 128), gSHd(T_TOK / 128, H_DIM / 128);
    const dim3 gRT(MAX_TILES, I_DIM / 128), gRTd(MAX_TILES, H_DIM / 128);

    if (fused) {
        // shared: gate+up fused -> down
        conv_kernel<<<nI4 / 256, 256, 0, stream>>>(shared_gate, wbufA, nI4);
        conv_kernel<<<nI4 / 256, 256, 0, stream>>>(shared_up, wbufB, nI4);
        gateup_fused<H_DIM><<<gSH, 512, 0, stream>>>(xb, wbufA, wbufB, hid, nullptr, nullptr);
        conv_kernel<<<nI4 / 256, 256, 0, stream>>>(shared_down, wbufA, nI4);
        gemm_k<2, I_DIM, H_DIM><<<gSHd, 256, 0, stream>>>(
            hid, wbufA, nullptr, out, nullptr, nullptr, nullptr, nullptr, 0);
        // routed: gate+up fused -> down k0/k1
        conv_kernel<<<nE4 / 256, 256, 0, stream>>>(expert_gate, wbufA, nE4);
        conv_kernel<<<nE4 / 256, 256, 0, stream>>>(expert_up, wbufB, nE4);
        gateup_fused<H_DIM><<<gRT, 512, 0, stream>>>(xb, wbufA, wbufB, hid, token_ids, tile_e);
        conv_kernel<<<nE4 / 256, 256, 0, stream>>>(expert_down, wbufA, nE4);
        gemm_k<3, I_DIM, H_DIM><<<gRTd, 256, 0, stream>>>(
            hid, wbufA, nullptr, out, token_ids, token_w, tile_e, tile_k, 0);
        gemm_k<3, I_DIM, H_DIM><<<gRTd, 256, 0, stream>>>(
            hid, wbufA, nullptr, out, token_ids, token_w, tile_e, tile_k, 1);
    } else {
        // R5-proven unfused sequence (single weight buffer)
        conv_kernel<<<nI4 / 256, 256, 0, stream>>>(shared_gate, wbufA, nI4);
        gemm_k<0, H_DIM, I_DIM><<<gSH, 256, 0, stream>>>(
            xb, wbufA, hid, nullptr, nullptr, nullptr, nullptr, nullptr, 0);
        conv_kernel<<<nI4 / 256, 256, 0, stream>>>(shared_up, wbufA, nI4);
        gemm_k<1, H_DIM, I_DIM><<<gSH, 256, 0, stream>>>(
            xb, wbufA, hid, nullptr, nullptr, nullptr, nullptr, nullptr, 0);
        conv_kernel<<<nI4 / 256, 256, 0, stream>>>(shared_down, wbufA, nI4);
        gemm_k<2, I_DIM, H_DIM><<<gSHd, 256, 0, stream>>>(
            hid, wbufA, nullptr, out, nullptr, nullptr, nullptr, nullptr, 0);
        conv_kernel<<<nE4 / 256, 256, 0, stream>>>(expert_gate, wbufA, nE4);
        gemm_k<0, H_DIM, I_DIM><<<gRT, 256, 0, stream>>>(
            xb, wbufA, hid, nullptr, token_ids, token_w, tile_e, tile_k, 0);
        conv_kernel<<<nE4 / 256, 256, 0, stream>>>(expert_up, wbufA, nE4);
        gemm_k<1, H_DIM, I_DIM><<<gRT, 256, 0, stream>>>(
            xb, wbufA, hid, nullptr, token_ids, token_w, tile_e, tile_k, 0);
        conv_kernel<<<nE4 / 256, 256, 0, stream>>>(expert_down, wbufA, nE4);
        gemm_k<3, I_DIM, H_DIM><<<gRTd, 256, 0, stream>>>(
            hid, wbufA, nullptr, out, token_ids, token_w, tile_e, tile_k, 0);
        gemm_k<3, I_DIM, H_DIM><<<gRTd, 256, 0, stream>>>(
            hid, wbufA, nullptr, out, token_ids, token_w, tile_e, tile_k, 1);
    }
}

// Round 10
// 782.174 us; speedup vs baseline: 1.5364x; 1.1225x over previous
//
#include <hip/hip_runtime.h>
#include <hip/hip_bf16.h>
#include <math.h>

#define T_TOK 8192
#define H_DIM 1024
#define I_DIM 2816
#define N_EXP 8
#define NREG  16           // (expert, k) regions
#define CAP_SLOTS 18432    // 2*T + 16*128 alignment headroom
#define MAX_TILES 144      // CAP_SLOTS / 128

typedef __bf16 bf16x8 __attribute__((ext_vector_type(8)));
typedef __bf16 bf16x4 __attribute__((ext_vector_type(4)));
typedef float f32x4 __attribute__((ext_vector_type(4)));

__device__ inline void gload_lds16(const void* g, void* l) {
    __builtin_amdgcn_global_load_lds((const __attribute__((address_space(1))) void*)g,
                                     (__attribute__((address_space(3))) void*)l, 16, 0, 0);
}

// Bijective XCD-aware tile swizzle (m204).
__device__ inline void swz_tile(int& bx, int& by) {
    const int nx = gridDim.x;
    const int nwg = nx * gridDim.y;
    int lin = by * nx + bx;
    int q = nwg >> 3, r = nwg & 7, xcd = lin & 7, pos = lin >> 3;
    int swz = (xcd < r ? xcd * (q + 1) : r * (q + 1) + (xcd - r) * q) + pos;
    bx = swz % nx; by = swz / nx;
}

// f32 -> bf16, 4 elems/thread
__global__ void conv_kernel(const float* __restrict__ src, __bf16* __restrict__ dst, int n4) {
    int i = blockIdx.x * 256 + threadIdx.x;
    if (i < n4) {
        float4 v = ((const float4*)src)[i];
        bf16x4 o;
        o[0] = (__bf16)v.x; o[1] = (__bf16)v.y; o[2] = (__bf16)v.z; o[3] = (__bf16)v.w;
        ((bf16x4*)dst)[i] = o;
    }
}

// two-segment conv in one launch (saves a dispatch gap)
__global__ void conv2_kernel(const float* __restrict__ s0, __bf16* __restrict__ d0, int n40,
                             const float* __restrict__ s1, __bf16* __restrict__ d1, int n41) {
    int b0 = (n40 + 255) >> 8;
    const float* src; __bf16* dst; int i;
    if ((int)blockIdx.x < b0) { src = s0; dst = d0; i = blockIdx.x * 256 + threadIdx.x; if (i >= n40) return; }
    else { src = s1; dst = d1; i = (blockIdx.x - b0) * 256 + threadIdx.x; if (i >= n41) return; }
    float4 v = ((const float4*)src)[i];
    bf16x4 o;
    o[0] = (__bf16)v.x; o[1] = (__bf16)v.y; o[2] = (__bf16)v.z; o[3] = (__bf16)v.w;
    ((bf16x4*)dst)[i] = o;
}

// One wave per token: logits over 8 experts (float4-vectorized), softmax, top-2.
__global__ void router_kernel(const float* __restrict__ x, const float* __restrict__ gw,
                              int* __restrict__ topi, float* __restrict__ topw) {
    int t = blockIdx.x * 4 + (threadIdx.x >> 6);
    int lane = threadIdx.x & 63;
    if (t >= T_TOK) return;
    const float4* xr = (const float4*)(x + (size_t)t * H_DIM);
    float s[N_EXP];
#pragma unroll
    for (int e = 0; e < N_EXP; e++) s[e] = 0.0f;
#pragma unroll
    for (int j = 0; j < H_DIM / 256; ++j) {
        float4 xv = xr[j * 64 + lane];
#pragma unroll
        for (int e = 0; e < N_EXP; e++) {
            float4 gv = ((const float4*)(gw + (size_t)e * H_DIM))[j * 64 + lane];
            s[e] += xv.x * gv.x + xv.y * gv.y + xv.z * gv.z + xv.w * gv.w;
        }
    }
#pragma unroll
    for (int off = 32; off; off >>= 1) {
#pragma unroll
        for (int e = 0; e < N_EXP; e++) s[e] += __shfl_xor(s[e], off);
    }
    if (lane == 0) {
        float m = s[0];
#pragma unroll
        for (int e = 1; e < N_EXP; e++) m = fmaxf(m, s[e]);
        float p[N_EXP]; float sum = 0.0f;
#pragma unroll
        for (int e = 0; e < N_EXP; e++) { p[e] = expf(s[e] - m); sum += p[e]; }
#pragma unroll
        for (int e = 0; e < N_EXP; e++) p[e] /= sum;
        int i0 = 0;
#pragma unroll
        for (int e = 1; e < N_EXP; e++) if (p[e] > p[i0]) i0 = e;
        int i1 = (i0 == 0) ? 1 : 0;
#pragma unroll
        for (int e = 0; e < N_EXP; e++) if (e != i0 && p[e] > p[i1]) i1 = e;
        float rs = p[i0] + p[i1] + 1e-20f;
        topi[t * 2 + 0] = i0; topi[t * 2 + 1] = i1;
        topw[t * 2 + 0] = p[i0] / rs; topw[t * 2 + 1] = p[i1] / rs;
    }
}

// Single-wave routing build: histogram -> bases -> tiles -> slots (+ slot_of inverse).
__global__ void route_build_kernel(const int* __restrict__ topi, const float* __restrict__ topw,
                                   int* __restrict__ token_ids, float* __restrict__ token_w,
                                   int* __restrict__ slot_of,
                                   int* __restrict__ tile_e, int* __restrict__ tile_k) {
    __shared__ int h[64][NREG];
    __shared__ int bases[NREG];
    __shared__ int cur[64][NREG];
    const int lane = threadIdx.x;   // 0..63, single wave

    for (int i = lane; i < CAP_SLOTS; i += 64) token_ids[i] = -1;

#pragma unroll
    for (int r = 0; r < NREG; r++) h[lane][r] = 0;
    for (int i = 0; i < T_TOK * 2 / 64; i++) {
        int entry = i * 64 + lane;
        int r = topi[entry] * 2 + (entry & 1);
        h[lane][r]++;
    }
    __syncthreads();

    if (lane < NREG) {
        int c = 0;
        for (int l = 0; l < 64; l++) c += h[l][lane];
        bases[lane] = c;
    }
    __syncthreads();

    if (lane == 0) {
        int b = 0, t = 0;
        for (int r = 0; r < NREG; r++) {
            int c = bases[r];
            int nt = (c + 127) >> 7;
            bases[r] = b;
            for (int i = 0; i < nt; i++) { tile_e[t] = r >> 1; tile_k[t] = r & 1; t++; }
            b += nt << 7;
        }
        for (; t < MAX_TILES; t++) { tile_e[t] = -1; tile_k[t] = -1; }
    }
    __syncthreads();

    for (int r = 0; r < NREG; r++) {
        int s = bases[r];
        for (int l = 0; l < lane; l++) s += h[l][r];
        cur[lane][r] = s;
    }
    __syncthreads();

    for (int i = 0; i < T_TOK * 2 / 64; i++) {
        int entry = i * 64 + lane;
        int r = topi[entry] * 2 + (entry & 1);
        int slot = cur[lane][r]++;
        token_ids[slot] = entry >> 1;
        token_w[slot] = topw[entry];
        slot_of[entry] = slot;
    }
}

// out[t][h] += w0*r_out[s0][h] + w1*r_out[s1][h]
__global__ void combine_kernel(float* __restrict__ out, const __bf16* __restrict__ r_out,
                               const int* __restrict__ slot_of, const float* __restrict__ topw) {
    int gid = blockIdx.x * 256 + threadIdx.x;
    int t = gid >> 8;
    int hcol = (gid & 255) * 4;
    int s0 = slot_of[t * 2], s1 = slot_of[t * 2 + 1];
    float w0 = topw[t * 2], w1 = topw[t * 2 + 1];
    bf16x4 a = *(const bf16x4*)&r_out[(size_t)s0 * H_DIM + hcol];
    bf16x4 b = *(const bf16x4*)&r_out[(size_t)s1 * H_DIM + hcol];
    float4 o = *(float4*)&out[(size_t)t * H_DIM + hcol];
    o.x += w0 * (float)a[0] + w1 * (float)b[0];
    o.y += w0 * (float)a[1] + w1 * (float)b[1];
    o.z += w0 * (float)a[2] + w1 * (float)b[2];
    o.w += w0 * (float)a[3] + w1 * (float)b[3];
    *(float4*)&out[(size_t)t * H_DIM + hcol] = o;
}

// Fused gate+up GEMM (R8-proven): 128x128, BK=32, 8 waves of 64x32 on both mats.
template<int K>
__global__ __launch_bounds__(512, 3)
void gateup_fused(const __bf16* __restrict__ A,
                  const __bf16* __restrict__ Wg, const __bf16* __restrict__ Wu,
                  __bf16* __restrict__ hid,
                  const int* __restrict__ token_ids, const int* __restrict__ tile_e) {
    int bx = blockIdx.x, by = blockIdx.y;
    swz_tile(bx, by);
    int e = 0;
    if (tile_e) { e = tile_e[bx]; if (e < 0) return; }
    const int m0 = bx * 128, n0 = by * 128;

    __shared__ __bf16 As[2][128 * 32];
    __shared__ __bf16 Bg[2][128 * 32];
    __shared__ __bf16 Bu[2][128 * 32];

    const int tid = threadIdx.x, lane = tid & 63, wid = tid >> 6;
    const int wm = wid >> 2, wn = wid & 3;

    const int srow = tid >> 2;
    const int colb = (tid & 3) * 16;

    int ar;
    if (tile_e) {
        int t0 = token_ids[m0 + srow];
        ar = t0 < 0 ? 0 : t0;
    } else {
        ar = m0 + srow;
    }
    const char* pA = (const char*)A + (size_t)ar * (K * 2) + colb;
    const char* pG = (const char*)Wg + ((size_t)e * I_DIM + n0 + srow) * (K * 2) + colb;
    const char* pU = (const char*)Wu + ((size_t)e * I_DIM + n0 + srow) * (K * 2) + colb;
    const int ldsoff = wid * 1024;

    f32x4 accg[4][2], accu[4][2];
    const f32x4 z4 = {0.f, 0.f, 0.f, 0.f};
#pragma unroll
    for (int i = 0; i < 4; i++)
#pragma unroll
        for (int j = 0; j < 2; j++) { accg[i][j] = z4; accu[i][j] = z4; }

    constexpr int NT = K / 32;

    auto stage = [&](int buf, int kt) {
        const size_t ko = (size_t)kt * 64;
        gload_lds16(pA + ko, (char*)As[buf] + ldsoff);
        gload_lds16(pG + ko, (char*)Bg[buf] + ldsoff);
        gload_lds16(pU + ko, (char*)Bu[buf] + ldsoff);
    };

    auto compute = [&](int buf) {
        const int rA = wm * 64 + (lane & 15);
        const int rB = wn * 32 + (lane & 15);
        const int cK = (lane >> 4) * 8;
        bf16x8 a[4], g[2], u[2];
#pragma unroll
        for (int i = 0; i < 4; i++) a[i] = *(const bf16x8*)&As[buf][(rA + i * 16) * 32 + cK];
#pragma unroll
        for (int j = 0; j < 2; j++) {
            g[j] = *(const bf16x8*)&Bg[buf][(rB + j * 16) * 32 + cK];
            u[j] = *(const bf16x8*)&Bu[buf][(rB + j * 16) * 32 + cK];
        }
#pragma unroll
        for (int i = 0; i < 4; i++)
#pragma unroll
            for (int j = 0; j < 2; j++) {
                accg[i][j] = __builtin_amdgcn_mfma_f32_16x16x32_bf16(a[i], g[j], accg[i][j], 0, 0, 0);
                accu[i][j] = __builtin_amdgcn_mfma_f32_16x16x32_bf16(a[i], u[j], accu[i][j], 0, 0, 0);
            }
    };

    stage(0, 0);
    __syncthreads();
    int cur = 0;
    for (int kt = 0; kt < NT; ++kt) {
        if (kt + 1 < NT) stage(cur ^ 1, kt + 1);
        compute(cur);
        __syncthreads();
        cur ^= 1;
    }

    const int cb = lane & 15, rb = (lane >> 4) * 4;
#pragma unroll
    for (int i = 0; i < 4; i++)
#pragma unroll
        for (int j = 0; j < 2; j++)
#pragma unroll
            for (int r = 0; r < 4; r++) {
                const int row = wm * 64 + i * 16 + rb + r;
                const int col = n0 + wn * 32 + j * 16 + cb;
                float gv = accg[i][j][r];
                float uv = accu[i][j][r];
                float h = (gv / (1.0f + __expf(-gv))) * uv;
                hid[(size_t)(m0 + row) * I_DIM + col] = (__bf16)h;
            }
}

// m97-shape GEMM, XCD swizzle.
// EPI: 0=gate(silu->hid) 1=up(hid*=v) 2=down_shared(out=v,f32)
//      3=down_routed(hid[slot]=v, bf16, single pass)  4=down_routed_RMW(fallback k-split)
template<int EPI, int KDIM, int NBROWS>
__global__ __launch_bounds__(256, 4)
void gemm_k(const __bf16* __restrict__ A, const __bf16* __restrict__ B,
            __bf16* __restrict__ hid, float* __restrict__ out,
            const int* __restrict__ token_ids, const float* __restrict__ token_w,
            const int* __restrict__ tile_e, const int* __restrict__ tile_k, int ksel) {
    int bx = blockIdx.x, by = blockIdx.y;
    swz_tile(bx, by);
    int e = 0;
    if (tile_e) {
        e = tile_e[bx];
        if (e < 0) return;
        if (EPI == 4 && tile_k[bx] != ksel) return;
    }
    const int m0 = bx * 128, n0 = by * 128;

    __shared__ __bf16 As[2][128 * 32];
    __shared__ __bf16 Bs[2][128 * 32];

    const int tid = threadIdx.x, lane = tid & 63, wid = tid >> 6;
    const int wm = wid >> 1, wn = wid & 1;

    const int srow = wid * 16 + (lane >> 2);
    const int colb = (lane & 3) * 16;

    int ar0, ar1;
    if (EPI <= 1 && token_ids) {
        int t0 = token_ids[m0 + srow], t1 = token_ids[m0 + srow + 64];
        ar0 = t0 < 0 ? 0 : t0;
        ar1 = t1 < 0 ? 0 : t1;
    } else {
        ar0 = m0 + srow; ar1 = m0 + srow + 64;
    }
    const char* pA0 = (const char*)A + (size_t)ar0 * (KDIM * 2) + colb;
    const char* pA1 = (const char*)A + (size_t)ar1 * (KDIM * 2) + colb;
    const char* pB0 = (const char*)B + ((size_t)e * NBROWS + n0 + srow) * (KDIM * 2) + colb;
    const char* pB1 = pB0 + (size_t)64 * (KDIM * 2);
    const int ldsoff = wid * 1024;

    f32x4 acc[4][4];
    const f32x4 z4 = {0.f, 0.f, 0.f, 0.f};
#pragma unroll
    for (int i = 0; i < 4; i++)
#pragma unroll
        for (int j = 0; j < 4; j++) acc[i][j] = z4;

    constexpr int NT = KDIM / 32;

    auto stage = [&](int buf, int kt) {
        const size_t ko = (size_t)kt * 64;
        char* a_l = (char*)As[buf] + ldsoff;
        gload_lds16(pA0 + ko, a_l);
        gload_lds16(pA1 + ko, a_l + 4096);
        char* b_l = (char*)Bs[buf] + ldsoff;
        gload_lds16(pB0 + ko, b_l);
        gload_lds16(pB1 + ko, b_l + 4096);
    };

    auto compute = [&](int buf) {
        const int rA = wm * 64 + (lane & 15);
        const int rB = wn * 64 + (lane & 15);
        const int cK = (lane >> 4) * 8;
        bf16x8 a[4], b[4];
#pragma unroll
        for (int i = 0; i < 4; i++) a[i] = *(const bf16x8*)&As[buf][(rA + i * 16) * 32 + cK];
#pragma unroll
        for (int j = 0; j < 4; j++) b[j] = *(const bf16x8*)&Bs[buf][(rB + j * 16) * 32 + cK];
#pragma unroll
        for (int i = 0; i < 4; i++)
#pragma unroll
            for (int j = 0; j < 4; j++)
                acc[i][j] = __builtin_amdgcn_mfma_f32_16x16x32_bf16(a[i], b[j], acc[i][j], 0, 0, 0);
    };

    stage(0, 0);
    __syncthreads();
    int cur = 0;
    for (int kt = 0; kt < NT; ++kt) {
        if (kt + 1 < NT) stage(cur ^ 1, kt + 1);
        compute(cur);
        __syncthreads();
        cur ^= 1;
    }

    const int cb = lane & 15, rb = (lane >> 4) * 4;
#pragma unroll
    for (int i = 0; i < 4; i++)
#pragma unroll
        for (int j = 0; j < 4; j++)
#pragma unroll
            for (int r = 0; r < 4; r++) {
                const int row = wm * 64 + i * 16 + rb + r;
                const int col = n0 + wn * 64 + j * 16 + cb;
                float v = acc[i][j][r];
                if (EPI == 0) {
                    float sv = v / (1.0f + __expf(-v));
                    hid[(size_t)(m0 + row) * NBROWS + col] = (__bf16)sv;
                } else if (EPI == 1) {
                    size_t idx = (size_t)(m0 + row) * NBROWS + col;
                    hid[idx] = (__bf16)((float)hid[idx] * v);
                } else if (EPI == 2) {
                    out[(size_t)(m0 + row) * H_DIM + col] = v;
                } else if (EPI == 3) {
                    hid[(size_t)(m0 + row) * H_DIM + col] = (__bf16)v;  // r_out slot row
                } else {
                    int slot = m0 + row;
                    int tok = token_ids[slot];
                    if (tok >= 0) {
                        size_t o = (size_t)tok * H_DIM + col;
                        out[o] += token_w[slot] * v;
                    }
                }
            }
}

extern "C" void kernel_launch(void* const* d_in, const int* in_sizes, int n_in,
                              void* d_out, int out_size, void* d_ws, size_t ws_size,
                              hipStream_t stream) {
    const float* x = (const float*)d_in[0];
    const float* gate_w = (const float*)d_in[1];
    const float* expert_gate = (const float*)d_in[2];
    const float* expert_up = (const float*)d_in[3];
    const float* expert_down = (const float*)d_in[4];
    const float* shared_gate = (const float*)d_in[5];
    const float* shared_up = (const float*)d_in[6];
    const float* shared_down = (const float*)d_in[7];
    float* out = (float*)d_out;

    char* w = (char*)d_ws;
    size_t off = 0;
    auto alloc = [&](size_t bytes) {
        void* p = w + off;
        off = (off + bytes + 255) & ~(size_t)255;
        return p;
    };

    const size_t wsz = (size_t)N_EXP * I_DIM * H_DIM * 2;   // 46.1 MB
    __bf16* xb = (__bf16*)alloc((size_t)T_TOK * H_DIM * 2);
    __bf16* wbufA = (__bf16*)alloc(wsz);
    __bf16* hid = (__bf16*)alloc((size_t)CAP_SLOTS * I_DIM * 2);
    int* topi = (int*)alloc((size_t)T_TOK * 2 * 4);
    float* topw = (float*)alloc((size_t)T_TOK * 2 * 4);
    int* slot_of = (int*)alloc((size_t)T_TOK * 2 * 4);
    int* tile_e = (int*)alloc(MAX_TILES * 4);
    int* tile_k = (int*)alloc(MAX_TILES * 4);
    int* token_ids = (int*)alloc((size_t)CAP_SLOTS * 4);
    float* token_w = (float*)alloc((size_t)CAP_SLOTS * 4);
    __bf16* wbufB = (__bf16*)alloc(wsz);               // fused path only
    const bool fused = (ws_size >= off);               // ~214 MB needed (R7/R8 proved fits)
    // r_out aliases wbufB (dead after routed gateup): CAP*1024*2 = 37.8 <= 46.1 MB
    __bf16* r_out = wbufB;

    conv_kernel<<<T_TOK * H_DIM / 1024, 256, 0, stream>>>(x, xb, T_TOK * H_DIM / 4);
    router_kernel<<<T_TOK / 4, 256, 0, stream>>>(x, gate_w, topi, topw);
    route_build_kernel<<<1, 64, 0, stream>>>(topi, topw, token_ids, token_w, slot_of, tile_e, tile_k);

    const int nI4 = I_DIM * H_DIM / 4;
    const int nE4 = N_EXP * I_DIM * H_DIM / 4;
    const dim3 gSH(T_TOK / 128, I_DIM / 128), gSHd(T_TOK / 128, H_DIM / 128);
    const dim3 gRT(MAX_TILES, I_DIM / 128), gRTd(MAX_TILES, H_DIM / 128);

    if (fused) {
        // shared: gate+up fused -> down (f32 out direct)
        conv2_kernel<<<2 * (nI4 / 256), 256, 0, stream>>>(shared_gate, wbufA, nI4, shared_up, wbufB, nI4);
        gateup_fused<H_DIM><<<gSH, 512, 0, stream>>>(xb, wbufA, wbufB, hid, nullptr, nullptr);
        conv_kernel<<<nI4 / 256, 256, 0, stream>>>(shared_down, wbufA, nI4);
        gemm_k<2, I_DIM, H_DIM><<<gSHd, 256, 0, stream>>>(
            hid, wbufA, nullptr, out, nullptr, nullptr, nullptr, nullptr, 0);
        // routed: gate+up fused -> down (bf16 slot rows, single pass) -> combine
        conv2_kernel<<<2 * (nE4 / 256), 256, 0, stream>>>(expert_gate, wbufA, nE4, expert_up, wbufB, nE4);
        gateup_fused<H_DIM><<<gRT, 512, 0, stream>>>(xb, wbufA, wbufB, hid, token_ids, tile_e);
        conv_kernel<<<nE4 / 256, 256, 0, stream>>>(expert_down, wbufA, nE4);
        gemm_k<3, I_DIM, H_DIM><<<gRTd, 256, 0, stream>>>(
            hid, wbufA, r_out, nullptr, nullptr, nullptr, tile_e, nullptr, 0);
        combine_kernel<<<T_TOK * H_DIM / 1024, 256, 0, stream>>>(out, r_out, slot_of, topw);
    } else {
        // R5-proven unfused fallback (single weight buffer, k-split RMW downs)
        conv_kernel<<<nI4 / 256, 256, 0, stream>>>(shared_gate, wbufA, nI4);
        gemm_k<0, H_DIM, I_DIM><<<gSH, 256, 0, stream>>>(
            xb, wbufA, hid, nullptr, nullptr, nullptr, nullptr, nullptr, 0);
        conv_kernel<<<nI4 / 256, 256, 0, stream>>>(shared_up, wbufA, nI4);
        gemm_k<1, H_DIM, I_DIM><<<gSH, 256, 0, stream>>>(
            xb, wbufA, hid, nullptr, nullptr, nullptr, nullptr, nullptr, 0);
        conv_kernel<<<nI4 / 256, 256, 0, stream>>>(shared_down, wbufA, nI4);
        gemm_k<2, I_DIM, H_DIM><<<gSHd, 256, 0, stream>>>(
            hid, wbufA, nullptr, out, nullptr, nullptr, nullptr, nullptr, 0);
        conv_kernel<<<nE4 / 256, 256, 0, stream>>>(expert_gate, wbufA, nE4);
        gemm_k<0, H_DIM, I_DIM><<<gRT, 256, 0, stream>>>(
            xb, wbufA, hid, nullptr, token_ids, token_w, tile_e, tile_k, 0);
        conv_kernel<<<nE4 / 256, 256, 0, stream>>>(expert_up, wbufA, nE4);
        gemm_k<1, H_DIM, I_DIM><<<gRT, 256, 0, stream>>>(
            xb, wbufA, hid, nullptr, token_ids, token_w, tile_e, tile_k, 0);
        conv_kernel<<<nE4 / 256, 256, 0, stream>>>(expert_down, wbufA, nE4);
        gemm_k<4, I_DIM, H_DIM><<<gRTd, 256, 0, stream>>>(
            hid, wbufA, nullptr, out, token_ids, token_w, tile_e, tile_k, 0);
        gemm_k<4, I_DIM, H_DIM><<<gRTd, 256, 0, stream>>>(
            hid, wbufA, nullptr, out, token_ids, token_w, tile_e, tile_k, 1);
    }
}